// Round 7
// baseline (119.207 us; speedup 1.0000x reference)
//
#include <hip/hip_runtime.h>
#include <hip/hip_bf16.h>

typedef short short8 __attribute__((ext_vector_type(8)));
typedef float f32x16 __attribute__((ext_vector_type(16)));

#define ND 128
#define LD 128
#define EE 128
#define NQ 128
#define LQ 32
#define STRIDE 136     // bf16 elems/row: 272B = 17*16B, b128-aligned, breaks pow2
#define HROWS 64       // rows per half-tile (pipeline stage)
#define HELEMS (HROWS * EE)   // 8192 elems per half

// ---- Kernel 1: query fp32 [E][Lq] -> bf16 [Lq][E] via LDS transpose (128 blocks) ----
__global__ __launch_bounds__(256)
void qconvert_kernel(const float* __restrict__ qry, __hip_bfloat16* __restrict__ qB) {
  __shared__ float s[LQ][EE + 1];            // 32 x 129 fp32
  const int q   = blockIdx.x;
  const int tid = threadIdx.x;
  const float* src = qry + q * (EE * LQ);
  #pragma unroll
  for (int i = 0; i < 4; ++i) {              // coalesced float4 read of [E][L]
    int c = i * 256 + tid;
    int e = c >> 3;
    int l = (c & 7) << 2;
    float4 v = reinterpret_cast<const float4*>(src)[c];
    s[l + 0][e] = v.x;
    s[l + 1][e] = v.y;
    s[l + 2][e] = v.z;
    s[l + 3][e] = v.w;
  }
  __syncthreads();
  __hip_bfloat16* dst = qB + q * (LQ * EE);
  #pragma unroll
  for (int i = 0; i < 4; ++i) {              // coalesced ushort4 write of [L][E]
    int c = i * 256 + tid;
    int l = c >> 5;
    int e = (c & 31) << 2;
    union { ushort4 u; __hip_bfloat16 b[4]; } o;
    o.b[0] = __float2bfloat16(s[l][e + 0]);
    o.b[1] = __float2bfloat16(s[l][e + 1]);
    o.b[2] = __float2bfloat16(s[l][e + 2]);
    o.b[3] = __float2bfloat16(s[l][e + 3]);
    reinterpret_cast<ushort4*>(dst)[c] = o.u;
  }
}

// ---- Kernel 2: fused maxsim, 32x32x16 MFMA, query-resident, 4-segment pipeline.
// Block = 256 threads = (2 docs x 2 half-tiles as 4 segments, 8 queries).
// Grid 64x16 = 1024 blocks = 4/CU co-resident (LDS 2*17408B*4blk=136KB<=160KB;
// __launch_bounds__(256,4) pins 4 waves/SIMD; demand ~126 regs <= 128 budget).
// While computing segment s from sdoc[s&1], segment s+1 is loaded (fp32, <=16
// regs in flight), cvt'd, and ds_written to sdoc[(s+1)&1] — staging hides
// under 32 MFMAs/wave; one barrier per segment. ----
__global__ __launch_bounds__(256, 4)
void maxsim_kernel(const float* __restrict__ doc,
                   const __hip_bfloat16* __restrict__ qB,
                   float* __restrict__ out) {
  __shared__ __hip_bfloat16 sdoc[2][HROWS * STRIDE];
  const int d0   = blockIdx.x * 2;
  const int qblk = blockIdx.y;
  const int tid  = threadIdx.x;
  const int wave = tid >> 6;
  const int lane = tid & 63;
  const int ln31 = lane & 31;        // m (A rows) / n (B cols = query token l)
  const int kh   = lane >> 5;        // k-group: k = kh*8 + j
  const int q0   = qblk * 8 + wave * 2;

  // B-frags, 32x32x16 layout: B[n=lane&31][k=ks*16+kh*8+j]. 2 queries x 8 ks
  // = 64 VGPRs, loaded ONCE and held for the whole kernel.
  short8 bfrag[2][8];
  #pragma unroll
  for (int qq = 0; qq < 2; ++qq) {
    const __hip_bfloat16* qp = qB + (q0 + qq) * (LQ * EE) + ln31 * EE + kh * 8;
    #pragma unroll
    for (int ks = 0; ks < 8; ++ks)
      bfrag[qq][ks] = *reinterpret_cast<const short8*>(qp + ks * 16);
  }

  float4 pf[4];                      // staging in-flight regs (16 VGPRs max)
  float colmax0 = -3.0e38f, colmax1 = -3.0e38f;

  // Issue 4 float4 loads (group grp of segment seg). seg: doc d0+(seg>>1),
  // rows (seg&1)*64 .. +63. chunk c = phase*256+tid, phase = grp*2+i.
  auto issue = [&](int seg, int grp) {
    const float4* src = reinterpret_cast<const float4*>(
        doc + (d0 + (seg >> 1)) * (LD * EE) + (seg & 1) * HELEMS);
    #pragma unroll
    for (int i = 0; i < 2; ++i) {
      int c = (grp * 2 + i) * 256 + tid;
      pf[2 * i]     = src[2 * c];
      pf[2 * i + 1] = src[2 * c + 1];
    }
  };
  // Convert the 4 in-flight float4 to 8 bf16 chunks, write to sdoc[seg&1].
  auto flush = [&](int seg, int grp) {
    __hip_bfloat16* dst = sdoc[seg & 1];
    #pragma unroll
    for (int i = 0; i < 2; ++i) {
      int c = (grp * 2 + i) * 256 + tid;
      float4 v0 = pf[2 * i], v1 = pf[2 * i + 1];
      union { uint4 u; __hip_bfloat16 b[8]; } o;
      o.b[0] = __float2bfloat16(v0.x);
      o.b[1] = __float2bfloat16(v0.y);
      o.b[2] = __float2bfloat16(v0.z);
      o.b[3] = __float2bfloat16(v0.w);
      o.b[4] = __float2bfloat16(v1.x);
      o.b[5] = __float2bfloat16(v1.y);
      o.b[6] = __float2bfloat16(v1.z);
      o.b[7] = __float2bfloat16(v1.w);
      *reinterpret_cast<uint4*>(&dst[(c >> 4) * STRIDE + ((c & 15) << 3)]) = o.u;
    }
  };
  // One 32-row m-tile of segment seg: 8 ks x 2 MFMA, fold rows into colmax.
  auto compute_mt = [&](int seg, int mt) {
    const __hip_bfloat16* sp = sdoc[seg & 1];
    f32x16 acc0 = {0.f, 0.f, 0.f, 0.f, 0.f, 0.f, 0.f, 0.f,
                   0.f, 0.f, 0.f, 0.f, 0.f, 0.f, 0.f, 0.f};
    f32x16 acc1 = acc0;
    #pragma unroll
    for (int ks = 0; ks < 8; ++ks) {
      short8 a = *reinterpret_cast<const short8*>(
          &sp[(mt * 32 + ln31) * STRIDE + ks * 16 + kh * 8]);
      acc0 = __builtin_amdgcn_mfma_f32_32x32x16_bf16(a, bfrag[0][ks], acc0, 0, 0, 0);
      acc1 = __builtin_amdgcn_mfma_f32_32x32x16_bf16(a, bfrag[1][ks], acc1, 0, 0, 0);
    }
    float t0 = fmaxf(fmaxf(fmaxf(acc0[0], acc0[1]), fmaxf(acc0[2], acc0[3])),
                     fmaxf(fmaxf(acc0[4], acc0[5]), fmaxf(acc0[6], acc0[7])));
    float u0 = fmaxf(fmaxf(fmaxf(acc0[8], acc0[9]), fmaxf(acc0[10], acc0[11])),
                     fmaxf(fmaxf(acc0[12], acc0[13]), fmaxf(acc0[14], acc0[15])));
    colmax0 = fmaxf(colmax0, fmaxf(t0, u0));
    float t1 = fmaxf(fmaxf(fmaxf(acc1[0], acc1[1]), fmaxf(acc1[2], acc1[3])),
                     fmaxf(fmaxf(acc1[4], acc1[5]), fmaxf(acc1[6], acc1[7])));
    float u1 = fmaxf(fmaxf(fmaxf(acc1[8], acc1[9]), fmaxf(acc1[10], acc1[11])),
                     fmaxf(fmaxf(acc1[12], acc1[13]), fmaxf(acc1[14], acc1[15])));
    colmax1 = fmaxf(colmax1, fmaxf(t1, u1));
  };

  // Prologue: stage segment 0 fully into sdoc[0].
  issue(0, 0); flush(0, 0);
  issue(0, 1); flush(0, 1);
  __syncthreads();

  // Pipeline: compute seg from sdoc[seg&1] while staging seg+1 to the other
  // buffer. Buffer seg+1 targets was last read in seg-1 (barrier-protected).
  #pragma unroll
  for (int seg = 0; seg < 4; ++seg) {
    if (seg < 3) issue(seg + 1, 0);
    compute_mt(seg, 0);
    if (seg < 3) { flush(seg + 1, 0); issue(seg + 1, 1); }
    compute_mt(seg, 1);
    if (seg < 3) flush(seg + 1, 1);

    if (seg & 1) {
      // Doc d0 + (seg>>1) finished: epilogue. C/D rows r=(reg&3)+8*(reg>>2)+4*kh
      // folded already; xor32 merges kh halves -> per-col max over 128 tokens;
      // sum 32 cols via xor 1/2/4/8/16.
      const int d = d0 + (seg >> 1);
      float m = fmaxf(colmax0, __shfl_xor(colmax0, 32, 64));
      float s = m;
      s += __shfl_xor(s, 1, 64);
      s += __shfl_xor(s, 2, 64);
      s += __shfl_xor(s, 4, 64);
      s += __shfl_xor(s, 8, 64);
      s += __shfl_xor(s, 16, 64);
      if (lane == 0) out[q0 * ND + d] = s;
      float m1 = fmaxf(colmax1, __shfl_xor(colmax1, 32, 64));
      float s1 = m1;
      s1 += __shfl_xor(s1, 1, 64);
      s1 += __shfl_xor(s1, 2, 64);
      s1 += __shfl_xor(s1, 4, 64);
      s1 += __shfl_xor(s1, 8, 64);
      s1 += __shfl_xor(s1, 16, 64);
      if (lane == 0) out[(q0 + 1) * ND + d] = s1;
      colmax0 = -3.0e38f;
      colmax1 = -3.0e38f;
    }
    __syncthreads();
  }
}

extern "C" void kernel_launch(void* const* d_in, const int* in_sizes, int n_in,
                              void* d_out, int out_size, void* d_ws, size_t ws_size,
                              hipStream_t stream) {
  const float* doc = (const float*)d_in[0];   // [128,128,128] fp32
  const float* qry = (const float*)d_in[1];   // [128,128,32]  fp32
  float* out = (float*)d_out;                 // [128,128]     fp32

  __hip_bfloat16* qB = (__hip_bfloat16*)d_ws; // 1 MiB: query bf16 [Nq][Lq][E]

  qconvert_kernel<<<dim3(NQ), dim3(256), 0, stream>>>(qry, qB);
  maxsim_kernel<<<dim3(ND / 2, NQ / 8), dim3(256), 0, stream>>>(doc, qB, out);
}

// Round 8
// 79.755 us; speedup vs baseline: 1.4947x; 1.4947x over previous
//
#include <hip/hip_runtime.h>
#include <hip/hip_bf16.h>

typedef short short8 __attribute__((ext_vector_type(8)));
typedef float f32x16 __attribute__((ext_vector_type(16)));

#define ND 128
#define LD 128
#define EE 128
#define NQ 128
#define LQ 32
#define STRIDE 136     // bf16 elems/row: 272B = 17*16B, b128-aligned, breaks pow2
#define HROWS 64       // rows per half-tile (pipeline stage)
#define HELEMS (HROWS * EE)   // 8192 elems per half

// ---- Kernel 1: query fp32 [E][Lq] -> bf16 [Lq][E] via LDS transpose (128 blocks) ----
__global__ __launch_bounds__(256)
void qconvert_kernel(const float* __restrict__ qry, __hip_bfloat16* __restrict__ qB) {
  __shared__ float s[LQ][EE + 1];            // 32 x 129 fp32
  const int q   = blockIdx.x;
  const int tid = threadIdx.x;
  const float* src = qry + q * (EE * LQ);
  #pragma unroll
  for (int i = 0; i < 4; ++i) {              // coalesced float4 read of [E][L]
    int c = i * 256 + tid;
    int e = c >> 3;
    int l = (c & 7) << 2;
    float4 v = reinterpret_cast<const float4*>(src)[c];
    s[l + 0][e] = v.x;
    s[l + 1][e] = v.y;
    s[l + 2][e] = v.z;
    s[l + 3][e] = v.w;
  }
  __syncthreads();
  __hip_bfloat16* dst = qB + q * (LQ * EE);
  #pragma unroll
  for (int i = 0; i < 4; ++i) {              // coalesced ushort4 write of [L][E]
    int c = i * 256 + tid;
    int l = c >> 5;
    int e = (c & 31) << 2;
    union { ushort4 u; __hip_bfloat16 b[4]; } o;
    o.b[0] = __float2bfloat16(s[l][e + 0]);
    o.b[1] = __float2bfloat16(s[l][e + 1]);
    o.b[2] = __float2bfloat16(s[l][e + 2]);
    o.b[3] = __float2bfloat16(s[l][e + 3]);
    reinterpret_cast<ushort4*>(dst)[c] = o.u;
  }
}

// ---- Kernel 2: fused maxsim, 32x32x16 MFMA, query-resident, 4-segment pipeline.
// Block = 256 threads = (2 docs x 2 half-tiles as 4 segments, 8 queries).
// Grid 64x16 = 1024 blocks. LDS 2*17408B: at 4 blocks/CU = 139KB <= 160KB.
// NO min-waves bound: R2 and R7 both proved that forcing the 128-reg budget
// (demand ~122-130) makes the allocator split 64 arch + 64 acc and spill
// bfrag -> ~90MB scratch traffic. Let the allocator pick 3-4 waves/SIMD.
// While computing segment s from sdoc[s&1], segment s+1 is loaded (fp32, 16
// regs in flight), cvt'd, and ds_written to sdoc[(s+1)&1] — staging hides
// under 32 MFMAs/wave; one barrier per segment. ----
__global__ __launch_bounds__(256)
void maxsim_kernel(const float* __restrict__ doc,
                   const __hip_bfloat16* __restrict__ qB,
                   float* __restrict__ out) {
  __shared__ __hip_bfloat16 sdoc[2][HROWS * STRIDE];
  const int d0   = blockIdx.x * 2;
  const int qblk = blockIdx.y;
  const int tid  = threadIdx.x;
  const int wave = tid >> 6;
  const int lane = tid & 63;
  const int ln31 = lane & 31;        // m (A rows) / n (B cols = query token l)
  const int kh   = lane >> 5;        // k-group: k = kh*8 + j
  const int q0   = qblk * 8 + wave * 2;

  // B-frags, 32x32x16 layout: B[n=lane&31][k=ks*16+kh*8+j]. 2 queries x 8 ks
  // = 64 VGPRs, loaded ONCE and held for the whole kernel.
  short8 bfrag[2][8];
  #pragma unroll
  for (int qq = 0; qq < 2; ++qq) {
    const __hip_bfloat16* qp = qB + (q0 + qq) * (LQ * EE) + ln31 * EE + kh * 8;
    #pragma unroll
    for (int ks = 0; ks < 8; ++ks)
      bfrag[qq][ks] = *reinterpret_cast<const short8*>(qp + ks * 16);
  }

  float4 pf[4];                      // staging in-flight regs (16 VGPRs)
  float colmax0 = -3.0e38f, colmax1 = -3.0e38f;

  // Issue 4 float4 loads (group grp of segment seg). seg: doc d0+(seg>>1),
  // rows (seg&1)*64 .. +63. chunk c = phase*256+tid, phase = grp*2+i.
  auto issue = [&](int seg, int grp) {
    const float4* src = reinterpret_cast<const float4*>(
        doc + (d0 + (seg >> 1)) * (LD * EE) + (seg & 1) * HELEMS);
    #pragma unroll
    for (int i = 0; i < 2; ++i) {
      int c = (grp * 2 + i) * 256 + tid;
      pf[2 * i]     = src[2 * c];
      pf[2 * i + 1] = src[2 * c + 1];
    }
  };
  // Convert the 4 in-flight float4 to 8 bf16 chunks, write to sdoc[seg&1].
  auto flush = [&](int seg, int grp) {
    __hip_bfloat16* dst = sdoc[seg & 1];
    #pragma unroll
    for (int i = 0; i < 2; ++i) {
      int c = (grp * 2 + i) * 256 + tid;
      float4 v0 = pf[2 * i], v1 = pf[2 * i + 1];
      union { uint4 u; __hip_bfloat16 b[8]; } o;
      o.b[0] = __float2bfloat16(v0.x);
      o.b[1] = __float2bfloat16(v0.y);
      o.b[2] = __float2bfloat16(v0.z);
      o.b[3] = __float2bfloat16(v0.w);
      o.b[4] = __float2bfloat16(v1.x);
      o.b[5] = __float2bfloat16(v1.y);
      o.b[6] = __float2bfloat16(v1.z);
      o.b[7] = __float2bfloat16(v1.w);
      *reinterpret_cast<uint4*>(&dst[(c >> 4) * STRIDE + ((c & 15) << 3)]) = o.u;
    }
  };
  // One 32-row m-tile of segment seg: 8 ks x 2 MFMA, fold rows into colmax.
  auto compute_mt = [&](int seg, int mt) {
    const __hip_bfloat16* sp = sdoc[seg & 1];
    f32x16 acc0 = {0.f, 0.f, 0.f, 0.f, 0.f, 0.f, 0.f, 0.f,
                   0.f, 0.f, 0.f, 0.f, 0.f, 0.f, 0.f, 0.f};
    f32x16 acc1 = acc0;
    #pragma unroll
    for (int ks = 0; ks < 8; ++ks) {
      short8 a = *reinterpret_cast<const short8*>(
          &sp[(mt * 32 + ln31) * STRIDE + ks * 16 + kh * 8]);
      acc0 = __builtin_amdgcn_mfma_f32_32x32x16_bf16(a, bfrag[0][ks], acc0, 0, 0, 0);
      acc1 = __builtin_amdgcn_mfma_f32_32x32x16_bf16(a, bfrag[1][ks], acc1, 0, 0, 0);
    }
    float t0 = fmaxf(fmaxf(fmaxf(acc0[0], acc0[1]), fmaxf(acc0[2], acc0[3])),
                     fmaxf(fmaxf(acc0[4], acc0[5]), fmaxf(acc0[6], acc0[7])));
    float u0 = fmaxf(fmaxf(fmaxf(acc0[8], acc0[9]), fmaxf(acc0[10], acc0[11])),
                     fmaxf(fmaxf(acc0[12], acc0[13]), fmaxf(acc0[14], acc0[15])));
    colmax0 = fmaxf(colmax0, fmaxf(t0, u0));
    float t1 = fmaxf(fmaxf(fmaxf(acc1[0], acc1[1]), fmaxf(acc1[2], acc1[3])),
                     fmaxf(fmaxf(acc1[4], acc1[5]), fmaxf(acc1[6], acc1[7])));
    float u1 = fmaxf(fmaxf(fmaxf(acc1[8], acc1[9]), fmaxf(acc1[10], acc1[11])),
                     fmaxf(fmaxf(acc1[12], acc1[13]), fmaxf(acc1[14], acc1[15])));
    colmax1 = fmaxf(colmax1, fmaxf(t1, u1));
  };

  // Prologue: stage segment 0 fully into sdoc[0].
  issue(0, 0); flush(0, 0);
  issue(0, 1); flush(0, 1);
  __syncthreads();

  // Pipeline: compute seg from sdoc[seg&1] while staging seg+1 to the other
  // buffer. The buffer seg+1 targets was last read in seg-1 (barrier-protected).
  #pragma unroll
  for (int seg = 0; seg < 4; ++seg) {
    if (seg < 3) issue(seg + 1, 0);
    compute_mt(seg, 0);
    if (seg < 3) { flush(seg + 1, 0); issue(seg + 1, 1); }
    compute_mt(seg, 1);
    if (seg < 3) flush(seg + 1, 1);

    if (seg & 1) {
      // Doc d0 + (seg>>1) done. C/D rows r=(reg&3)+8*(reg>>2)+4*kh already
      // folded; xor32 merges kh halves -> per-col max over 128 tokens; sum
      // 32 cols via xor 1/2/4/8/16.
      const int d = d0 + (seg >> 1);
      float m = fmaxf(colmax0, __shfl_xor(colmax0, 32, 64));
      float s = m;
      s += __shfl_xor(s, 1, 64);
      s += __shfl_xor(s, 2, 64);
      s += __shfl_xor(s, 4, 64);
      s += __shfl_xor(s, 8, 64);
      s += __shfl_xor(s, 16, 64);
      if (lane == 0) out[q0 * ND + d] = s;
      float m1 = fmaxf(colmax1, __shfl_xor(colmax1, 32, 64));
      float s1 = m1;
      s1 += __shfl_xor(s1, 1, 64);
      s1 += __shfl_xor(s1, 2, 64);
      s1 += __shfl_xor(s1, 4, 64);
      s1 += __shfl_xor(s1, 8, 64);
      s1 += __shfl_xor(s1, 16, 64);
      if (lane == 0) out[(q0 + 1) * ND + d] = s1;
      colmax0 = -3.0e38f;
      colmax1 = -3.0e38f;
    }
    __syncthreads();
  }
}

extern "C" void kernel_launch(void* const* d_in, const int* in_sizes, int n_in,
                              void* d_out, int out_size, void* d_ws, size_t ws_size,
                              hipStream_t stream) {
  const float* doc = (const float*)d_in[0];   // [128,128,128] fp32
  const float* qry = (const float*)d_in[1];   // [128,128,32]  fp32
  float* out = (float*)d_out;                 // [128,128]     fp32

  __hip_bfloat16* qB = (__hip_bfloat16*)d_ws; // 1 MiB: query bf16 [Nq][Lq][E]

  qconvert_kernel<<<dim3(NQ), dim3(256), 0, stream>>>(qry, qB);
  maxsim_kernel<<<dim3(ND / 2, NQ / 8), dim3(256), 0, stream>>>(doc, qB, out);
}